// Round 1
// baseline (3643.642 us; speedup 1.0000x reference)
//
#include <hip/hip_runtime.h>
#include <stdint.h>
#include <math.h>

typedef _Float16 half_t;
typedef _Float16 f16x8 __attribute__((ext_vector_type(8)));
typedef float f32x4 __attribute__((ext_vector_type(4)));

#define SLOPE 0.01f

__device__ inline float leaky(float v) { return v > 0.f ? v : SLOPE * v; }

__device__ inline void stage16(const half_t* g, half_t* l) {
    __builtin_amdgcn_global_load_lds(
        (const __attribute__((address_space(1))) unsigned int*)g,
        (__attribute__((address_space(3))) unsigned int*)l, 16, 0, 0);
}

__device__ inline float softplusf(float v) {
    return v > 20.f ? v : log1pf(expf(v));
}

// ---------------------------------------------------------------------------
// Weight prep: cast/reorder conv weights to oc-major fp16 ("B^T" GEMM operand)
// ---------------------------------------------------------------------------
__global__ void prep_kernel(const float* __restrict__ W1, const float* __restrict__ W2,
                            const float* __restrict__ W3,
                            half_t* __restrict__ B1w, half_t* __restrict__ B2w,
                            half_t* __restrict__ B3w)
{
    const unsigned idx = blockIdx.x * 256u + threadIdx.x;
    const unsigned n2 = 768u * 6912u;                 // 5,308,416
    if (idx < n2) {
        unsigned oc = idx / 6912u;
        unsigned rem = idx - oc * 6912u;
        unsigned tap = rem / 768u;
        unsigned ic = rem - tap * 768u;
        unsigned ky = tap / 3u, kx = tap - ky * 3u;
        B2w[idx] = (half_t)W2[(((size_t)oc * 768u + ic) * 3u + ky) * 3u + kx];
    } else if (idx < n2 + 147456u) {
        unsigned i = idx - n2;
        B1w[i] = (half_t)W1[i];                       // W1 flat is already (oc,ic)
    } else if (idx < n2 + 294912u) {
        unsigned i = idx - n2 - 147456u;
        B3w[i] = (half_t)W3[i];                       // W3 flat is already (oc,ic)
    }
}

// ---------------------------------------------------------------------------
// Per-window linear attention. One block per window. Writes feat NHWC fp16.
// Pixel order is the reference's contiguous reinterpret: flat = n*64 + p.
// ---------------------------------------------------------------------------
__global__ __launch_bounds__(256, 2)
void attn_kernel(const float* __restrict__ x,
                 const float* __restrict__ Wq, const float* __restrict__ bq,
                 const float* __restrict__ Wk, const float* __restrict__ bk,
                 const float* __restrict__ Wv, const float* __restrict__ bv,
                 const float* __restrict__ Wo, const float* __restrict__ bo,
                 half_t* __restrict__ featN)
{
    __shared__ half_t xls[192 * 65];
    __shared__ float wqL[512], wkL[512], wvL[512], woL[512];
    __shared__ float bqL[8], bkL[8], bvL[8], boL[64];
    __shared__ float kls[192 * 9], vls[192 * 9];
    __shared__ float sls[64];

    const int t = threadIdx.x;
    const int blk = blockIdx.x;
    const int b = blk >> 10;
    const int n = blk & 1023;
    const int wi = n >> 5, wj = n & 31;

    for (int i = t; i < 512; i += 256) {
        wqL[i] = Wq[i]; wkL[i] = Wk[i]; wvL[i] = Wv[i]; woL[i] = Wo[i];
    }
    if (t < 8)  { bqL[t] = bq[t]; bkL[t] = bk[t]; bvL[t] = bv[t]; }
    if (t < 64) boL[t] = bo[t];

    // gather window pixels: channel c, patch row py -> 8 contiguous floats
    #pragma unroll
    for (int i = 0; i < 6; ++i) {
        int idx = t + i * 256;                 // 0..1535 = (c,py)
        int c = idx >> 3, py = idx & 7;
        const float* src = x + (((size_t)b * 192 + c) * 256 + (wi * 8 + py)) * 256 + wj * 8;
        float4 v0 = *(const float4*)src;
        float4 v1 = *(const float4*)(src + 4);
        half_t* dst = &xls[c * 65 + py * 8];
        dst[0] = (half_t)v0.x; dst[1] = (half_t)v0.y; dst[2] = (half_t)v0.z; dst[3] = (half_t)v0.w;
        dst[4] = (half_t)v1.x; dst[5] = (half_t)v1.y; dst[6] = (half_t)v1.z; dst[7] = (half_t)v1.w;
    }
    __syncthreads();

    float qf[8], kf[8], vf[8];
    if (t < 192) {
        #pragma unroll
        for (int d = 0; d < 8; ++d) { qf[d] = bqL[d]; kf[d] = bkL[d]; vf[d] = bvL[d]; }
        const half_t* xr = &xls[t * 65];
        for (int p = 0; p < 64; ++p) {
            float xv = (float)xr[p];
            const float* wqp = &wqL[p * 8];
            const float* wkp = &wkL[p * 8];
            const float* wvp = &wvL[p * 8];
            #pragma unroll
            for (int d = 0; d < 8; ++d) {
                qf[d] += xv * wqp[d];
                kf[d] += xv * wkp[d];
                vf[d] += xv * wvp[d];
            }
        }
        #pragma unroll
        for (int d = 0; d < 8; ++d) {
            qf[d] = softplusf(qf[d]);
            kf[d] = softplusf(kf[d]);
            kls[t * 9 + d] = kf[d];
            vls[t * 9 + d] = vf[d];
        }
    }
    __syncthreads();
    // S[e][d] = sum_c k[c][e] * v[c][d]   (linear-attention trick: 8x8 matrix)
    if (t < 64) {
        int e = t >> 3, dd = t & 7;
        float s = 0.f;
        for (int c = 0; c < 192; ++c) s += kls[c * 9 + e] * vls[c * 9 + dd];
        sls[t] = s;
    }
    __syncthreads();
    if (t < 192) {
        float rf[8];
        #pragma unroll
        for (int d = 0; d < 8; ++d) {
            float s = 0.f;
            #pragma unroll
            for (int e = 0; e < 8; ++e) s += qf[e] * sls[e * 8 + d];
            rf[d] = s;
        }
        half_t* xr = &xls[t * 65];
        for (int p = 0; p < 64; ++p) {
            float a = boL[p];
            #pragma unroll
            for (int d = 0; d < 8; ++d) a += rf[d] * woL[d * 64 + p];
            xr[p] = (half_t)((float)xr[p] + a);   // residual y = xp + attn
        }
    }
    __syncthreads();
    // write NHWC fp16: feat[(b*65536 + n*64 + p)*192 + c], coalesced
    half_t* dst = featN + ((size_t)b * 65536 + (size_t)n * 64) * 192;
    for (int i = 0; i < 48; ++i) {
        int idx = t + i * 256;                 // 0..12287 = p*192 + c
        int p = idx / 192, c = idx - p * 192;
        dst[idx] = xls[c * 65 + p];
    }
}

// ---------------------------------------------------------------------------
// conv1: 1x1 192->768 + leaky. GEMM M=65536 (one batch), N=768, K=192.
// Output into padded NHWC h1p (258x258x768), interior only.
// ---------------------------------------------------------------------------
__global__ __launch_bounds__(256, 2)
void conv1_kernel(const half_t* __restrict__ featN, const half_t* __restrict__ B1w,
                  const float* __restrict__ b1, half_t* __restrict__ h1p, int batch)
{
    __shared__ half_t As[128 * 64];
    __shared__ half_t Bs[128 * 64];
    const int t = threadIdx.x;
    const int lane = t & 63;
    const int w = t >> 6;
    const int m0 = blockIdx.x * 128;
    const int n0 = blockIdx.y * 128;
    const int wm = (w >> 1) * 64, wn = (w & 1) * 64;
    const int rbase = t >> 3;
    const int g = (t & 7) ^ (rbase & 7);       // inverse-swizzled source chunk
    const int ar = lane & 15, kc = lane >> 4;

    f32x4 acc[4][4];
    #pragma unroll
    for (int i = 0; i < 4; ++i)
        #pragma unroll
        for (int j = 0; j < 4; ++j) acc[i][j] = (f32x4){0.f, 0.f, 0.f, 0.f};

    const size_t mb = (size_t)batch * 65536 + m0;

    for (int s = 0; s < 3; ++s) {
        const int k0 = s * 64;
        const half_t* ga = featN + (mb + rbase) * 192 + k0 + g * 8;
        const half_t* gb = B1w + (size_t)(n0 + rbase) * 192 + k0 + g * 8;
        half_t* la = As + t * 8;
        half_t* lb = Bs + t * 8;
        #pragma unroll
        for (int i = 0; i < 4; ++i) {
            stage16(ga + (size_t)32 * i * 192, la + 2048 * i);
            stage16(gb + (size_t)32 * i * 192, lb + 2048 * i);
        }
        __syncthreads();
        #pragma unroll
        for (int kh = 0; kh < 2; ++kh) {
            f16x8 af[4], bfr[4];
            const int c = kh * 4 + kc;
            #pragma unroll
            for (int mf = 0; mf < 4; ++mf) {
                int r = wm + mf * 16 + ar;
                af[mf] = *(const f16x8*)&As[(r * 8 + (c ^ (r & 7))) * 8];
            }
            #pragma unroll
            for (int nf = 0; nf < 4; ++nf) {
                int r = wn + nf * 16 + ar;
                bfr[nf] = *(const f16x8*)&Bs[(r * 8 + (c ^ (r & 7))) * 8];
            }
            #pragma unroll
            for (int mf = 0; mf < 4; ++mf)
                #pragma unroll
                for (int nf = 0; nf < 4; ++nf)
                    acc[mf][nf] = __builtin_amdgcn_mfma_f32_16x16x32_f16(af[mf], bfr[nf], acc[mf][nf], 0, 0, 0);
        }
        __syncthreads();
    }

    const int y = m0 >> 8, x0 = m0 & 255;
    half_t* outrow = h1p + ((size_t)(y + 1) * 258 + (x0 + 1)) * 768;
    #pragma unroll
    for (int nf = 0; nf < 4; ++nf) {
        int n = n0 + wn + nf * 16 + ar;
        float bias = b1[n];
        #pragma unroll
        for (int mf = 0; mf < 4; ++mf) {
            #pragma unroll
            for (int r4 = 0; r4 < 4; ++r4) {
                int local = wm + mf * 16 + kc * 4 + r4;
                outrow[(size_t)local * 768 + n] = (half_t)leaky(acc[mf][nf][r4] + bias);
            }
        }
    }
}

// ---------------------------------------------------------------------------
// conv2: 3x3 SAME 768->768 + leaky, implicit GEMM on padded h1p.
// M=65536 (one batch), N=768, K=9*768=6912 (BK=64 -> 108 steps).
// ---------------------------------------------------------------------------
__global__ __launch_bounds__(256, 2)
void conv2_kernel(const half_t* __restrict__ h1p, const half_t* __restrict__ B2w,
                  const float* __restrict__ b2, half_t* __restrict__ h2)
{
    __shared__ half_t As[128 * 64];
    __shared__ half_t Bs[128 * 64];
    const int t = threadIdx.x;
    const int lane = t & 63;
    const int w = t >> 6;
    const int m0 = blockIdx.x * 128;
    const int n0 = blockIdx.y * 128;
    const int wm = (w >> 1) * 64, wn = (w & 1) * 64;
    const int rbase = t >> 3;
    const int g = (t & 7) ^ (rbase & 7);
    const int ar = lane & 15, kc = lane >> 4;
    const int y = m0 >> 8, x0 = m0 & 255;

    f32x4 acc[4][4];
    #pragma unroll
    for (int i = 0; i < 4; ++i)
        #pragma unroll
        for (int j = 0; j < 4; ++j) acc[i][j] = (f32x4){0.f, 0.f, 0.f, 0.f};

    int ky = 0, kx = 0, icc = 0;
    for (int s = 0; s < 108; ++s) {
        const int ic0 = icc * 64;
        const half_t* ga = h1p + ((size_t)(y + ky) * 258 + (x0 + kx + rbase)) * 768 + ic0 + g * 8;
        const half_t* gb = B2w + (size_t)(n0 + rbase) * 6912 + (ky * 3 + kx) * 768 + ic0 + g * 8;
        half_t* la = As + t * 8;
        half_t* lb = Bs + t * 8;
        #pragma unroll
        for (int i = 0; i < 4; ++i) {
            stage16(ga + (size_t)32 * i * 768, la + 2048 * i);
            stage16(gb + (size_t)32 * i * 6912, lb + 2048 * i);
        }
        __syncthreads();
        #pragma unroll
        for (int kh = 0; kh < 2; ++kh) {
            f16x8 af[4], bfr[4];
            const int c = kh * 4 + kc;
            #pragma unroll
            for (int mf = 0; mf < 4; ++mf) {
                int r = wm + mf * 16 + ar;
                af[mf] = *(const f16x8*)&As[(r * 8 + (c ^ (r & 7))) * 8];
            }
            #pragma unroll
            for (int nf = 0; nf < 4; ++nf) {
                int r = wn + nf * 16 + ar;
                bfr[nf] = *(const f16x8*)&Bs[(r * 8 + (c ^ (r & 7))) * 8];
            }
            #pragma unroll
            for (int mf = 0; mf < 4; ++mf)
                #pragma unroll
                for (int nf = 0; nf < 4; ++nf)
                    acc[mf][nf] = __builtin_amdgcn_mfma_f32_16x16x32_f16(af[mf], bfr[nf], acc[mf][nf], 0, 0, 0);
        }
        __syncthreads();
        if (++icc == 12) { icc = 0; if (++kx == 3) { kx = 0; ++ky; } }
    }

    half_t* outp = h2 + (size_t)m0 * 768;
    #pragma unroll
    for (int nf = 0; nf < 4; ++nf) {
        int n = n0 + wn + nf * 16 + ar;
        float bias = b2[n];
        #pragma unroll
        for (int mf = 0; mf < 4; ++mf) {
            #pragma unroll
            for (int r4 = 0; r4 < 4; ++r4) {
                int local = wm + mf * 16 + kc * 4 + r4;
                outp[(size_t)local * 768 + n] = (half_t)leaky(acc[mf][nf][r4] + bias);
            }
        }
    }
}

// ---------------------------------------------------------------------------
// conv3: 1x1 768->192 + leaky. GEMM M=65536 (one batch), N=192, K=768.
// Writes final NCHW fp32 output.
// ---------------------------------------------------------------------------
__global__ __launch_bounds__(256, 2)
void conv3_kernel(const half_t* __restrict__ h2, const half_t* __restrict__ B3w,
                  const float* __restrict__ b3, float* __restrict__ out, int batch)
{
    __shared__ half_t As[128 * 64];
    __shared__ half_t Bs[192 * 64];
    const int t = threadIdx.x;
    const int lane = t & 63;
    const int w = t >> 6;
    const int m0 = blockIdx.x * 128;
    const int wm = (w >> 1) * 64;      // 0 / 64
    const int wn = (w & 1) * 96;       // 0 / 96
    const int rbase = t >> 3;
    const int g = (t & 7) ^ (rbase & 7);
    const int ar = lane & 15, kc = lane >> 4;

    f32x4 acc[4][6];
    #pragma unroll
    for (int i = 0; i < 4; ++i)
        #pragma unroll
        for (int j = 0; j < 6; ++j) acc[i][j] = (f32x4){0.f, 0.f, 0.f, 0.f};

    for (int s = 0; s < 12; ++s) {
        const int k0 = s * 64;
        const half_t* ga = h2 + (size_t)(m0 + rbase) * 768 + k0 + g * 8;
        const half_t* gb = B3w + (size_t)rbase * 768 + k0 + g * 8;
        half_t* la = As + t * 8;
        half_t* lb = Bs + t * 8;
        #pragma unroll
        for (int i = 0; i < 4; ++i) stage16(ga + (size_t)32 * i * 768, la + 2048 * i);
        #pragma unroll
        for (int i = 0; i < 6; ++i) stage16(gb + (size_t)32 * i * 768, lb + 2048 * i);
        __syncthreads();
        #pragma unroll
        for (int kh = 0; kh < 2; ++kh) {
            f16x8 af[4], bfr[6];
            const int c = kh * 4 + kc;
            #pragma unroll
            for (int mf = 0; mf < 4; ++mf) {
                int r = wm + mf * 16 + ar;
                af[mf] = *(const f16x8*)&As[(r * 8 + (c ^ (r & 7))) * 8];
            }
            #pragma unroll
            for (int nf = 0; nf < 6; ++nf) {
                int r = wn + nf * 16 + ar;
                bfr[nf] = *(const f16x8*)&Bs[(r * 8 + (c ^ (r & 7))) * 8];
            }
            #pragma unroll
            for (int mf = 0; mf < 4; ++mf)
                #pragma unroll
                for (int nf = 0; nf < 6; ++nf)
                    acc[mf][nf] = __builtin_amdgcn_mfma_f32_16x16x32_f16(af[mf], bfr[nf], acc[mf][nf], 0, 0, 0);
        }
        __syncthreads();
    }

    #pragma unroll
    for (int nf = 0; nf < 6; ++nf) {
        int n = wn + nf * 16 + ar;
        float bias = b3[n];
        float* op = out + ((size_t)batch * 192 + n) * 65536 + m0;
        #pragma unroll
        for (int mf = 0; mf < 4; ++mf) {
            int local = wm + mf * 16 + kc * 4;
            f32x4 v;
            #pragma unroll
            for (int r4 = 0; r4 < 4; ++r4) v[r4] = leaky(acc[mf][nf][r4] + bias);
            *(f32x4*)(op + local) = v;
        }
    }
}

// ---------------------------------------------------------------------------
extern "C" void kernel_launch(void* const* d_in, const int* in_sizes, int n_in,
                              void* d_out, int out_size, void* d_ws, size_t ws_size,
                              hipStream_t stream)
{
    const float* x  = (const float*)d_in[0];
    const float* Wq = (const float*)d_in[1];
    const float* bq = (const float*)d_in[2];
    const float* Wk = (const float*)d_in[3];
    const float* bk = (const float*)d_in[4];
    const float* Wv = (const float*)d_in[5];
    const float* bv = (const float*)d_in[6];
    const float* Wo = (const float*)d_in[7];
    const float* bo = (const float*)d_in[8];
    const float* W1 = (const float*)d_in[9];
    const float* b1 = (const float*)d_in[10];
    const float* W2 = (const float*)d_in[11];
    const float* b2 = (const float*)d_in[12];
    const float* W3 = (const float*)d_in[13];
    const float* b3 = (const float*)d_in[14];

    char* ws = (char*)d_ws;
    const size_t OFF_B1   = 0;              // 147456 fp16 = 294,912 B
    const size_t OFF_B3   = 294912;         // 147456 fp16
    const size_t OFF_B2   = 589824;         // 5,308,416 fp16 = 10,616,832 B
    const size_t OFF_FEAT = 11206656;       // 4*65536*192 fp16 = 100,663,296 B
    const size_t OFF_H1P  = 111869952;      // 258*258*768 fp16 = 102,254,592 B (per-batch)
    const size_t OFF_H2   = 214124544;      // 65536*768 fp16 = 100,663,296 B (per-batch)
    const size_t WS_NEED  = 314787840;
    if (ws_size < WS_NEED) return;          // insufficient workspace — fail cleanly

    half_t* B1w   = (half_t*)(ws + OFF_B1);
    half_t* B3w   = (half_t*)(ws + OFF_B3);
    half_t* B2w   = (half_t*)(ws + OFF_B2);
    half_t* featN = (half_t*)(ws + OFF_FEAT);
    half_t* h1p   = (half_t*)(ws + OFF_H1P);
    half_t* h2    = (half_t*)(ws + OFF_H2);

    // zero padded h1 (border must be 0 for SAME conv); interior rewritten per batch
    hipMemsetAsync(h1p, 0, 102254592, stream);
    prep_kernel<<<21888, 256, 0, stream>>>(W1, W2, W3, B1w, B2w, B3w);
    attn_kernel<<<4096, 256, 0, stream>>>(x, Wq, bq, Wk, bk, Wv, bv, Wo, bo, featN);

    for (int b = 0; b < 4; ++b) {
        conv1_kernel<<<dim3(512, 6), 256, 0, stream>>>(featN, B1w, b1, h1p, b);
        conv2_kernel<<<dim3(512, 6), 256, 0, stream>>>(h1p, B2w, b2, h2);
        conv3_kernel<<<dim3(512, 1), 256, 0, stream>>>(h2, B3w, b3, (float*)d_out, b);
    }
}

// Round 2
// 3643.489 us; speedup vs baseline: 1.0000x; 1.0000x over previous
//
#include <hip/hip_runtime.h>
#include <stdint.h>
#include <math.h>

typedef _Float16 half_t;
typedef _Float16 f16x8 __attribute__((ext_vector_type(8)));
typedef float f32x4 __attribute__((ext_vector_type(4)));

#define SLOPE 0.01f

__device__ inline float leaky(float v) { return v > 0.f ? v : SLOPE * v; }

__device__ inline void stage16(const half_t* g, half_t* l) {
    __builtin_amdgcn_global_load_lds(
        (const __attribute__((address_space(1))) unsigned int*)g,
        (__attribute__((address_space(3))) unsigned int*)l, 16, 0, 0);
}

__device__ inline float softplusf(float v) {
    return v > 20.f ? v : log1pf(expf(v));
}

// ---------------------------------------------------------------------------
// Weight prep: cast/reorder conv weights to oc-major fp16 ("B^T" GEMM operand)
// ---------------------------------------------------------------------------
__global__ void prep_kernel(const float* __restrict__ W1, const float* __restrict__ W2,
                            const float* __restrict__ W3,
                            half_t* __restrict__ B1w, half_t* __restrict__ B2w,
                            half_t* __restrict__ B3w)
{
    const unsigned idx = blockIdx.x * 256u + threadIdx.x;
    const unsigned n2 = 768u * 6912u;                 // 5,308,416
    if (idx < n2) {
        unsigned oc = idx / 6912u;
        unsigned rem = idx - oc * 6912u;
        unsigned tap = rem / 768u;
        unsigned ic = rem - tap * 768u;
        unsigned ky = tap / 3u, kx = tap - ky * 3u;
        B2w[idx] = (half_t)W2[(((size_t)oc * 768u + ic) * 3u + ky) * 3u + kx];
    } else if (idx < n2 + 147456u) {
        unsigned i = idx - n2;
        B1w[i] = (half_t)W1[i];                       // W1 flat is already (oc,ic)
    } else if (idx < n2 + 294912u) {
        unsigned i = idx - n2 - 147456u;
        B3w[i] = (half_t)W3[i];                       // W3 flat is already (oc,ic)
    }
}

// ---------------------------------------------------------------------------
// Per-window linear attention. One block per window. Writes feat NHWC fp16.
// ---------------------------------------------------------------------------
__global__ __launch_bounds__(256, 2)
void attn_kernel(const float* __restrict__ x,
                 const float* __restrict__ Wq, const float* __restrict__ bq,
                 const float* __restrict__ Wk, const float* __restrict__ bk,
                 const float* __restrict__ Wv, const float* __restrict__ bv,
                 const float* __restrict__ Wo, const float* __restrict__ bo,
                 half_t* __restrict__ featN)
{
    __shared__ half_t xls[192 * 65];
    __shared__ float wqL[512], wkL[512], wvL[512], woL[512];
    __shared__ float bqL[8], bkL[8], bvL[8], boL[64];
    __shared__ float kls[192 * 9], vls[192 * 9];
    __shared__ float sls[64];

    const int t = threadIdx.x;
    const int blk = blockIdx.x;
    const int b = blk >> 10;
    const int n = blk & 1023;
    const int wi = n >> 5, wj = n & 31;

    for (int i = t; i < 512; i += 256) {
        wqL[i] = Wq[i]; wkL[i] = Wk[i]; wvL[i] = Wv[i]; woL[i] = Wo[i];
    }
    if (t < 8)  { bqL[t] = bq[t]; bkL[t] = bk[t]; bvL[t] = bv[t]; }
    if (t < 64) boL[t] = bo[t];

    #pragma unroll
    for (int i = 0; i < 6; ++i) {
        int idx = t + i * 256;                 // 0..1535 = (c,py)
        int c = idx >> 3, py = idx & 7;
        const float* src = x + (((size_t)b * 192 + c) * 256 + (wi * 8 + py)) * 256 + wj * 8;
        float4 v0 = *(const float4*)src;
        float4 v1 = *(const float4*)(src + 4);
        half_t* dst = &xls[c * 65 + py * 8];
        dst[0] = (half_t)v0.x; dst[1] = (half_t)v0.y; dst[2] = (half_t)v0.z; dst[3] = (half_t)v0.w;
        dst[4] = (half_t)v1.x; dst[5] = (half_t)v1.y; dst[6] = (half_t)v1.z; dst[7] = (half_t)v1.w;
    }
    __syncthreads();

    float qf[8], kf[8], vf[8];
    if (t < 192) {
        #pragma unroll
        for (int d = 0; d < 8; ++d) { qf[d] = bqL[d]; kf[d] = bkL[d]; vf[d] = bvL[d]; }
        const half_t* xr = &xls[t * 65];
        for (int p = 0; p < 64; ++p) {
            float xv = (float)xr[p];
            const float* wqp = &wqL[p * 8];
            const float* wkp = &wkL[p * 8];
            const float* wvp = &wvL[p * 8];
            #pragma unroll
            for (int d = 0; d < 8; ++d) {
                qf[d] += xv * wqp[d];
                kf[d] += xv * wkp[d];
                vf[d] += xv * wvp[d];
            }
        }
        #pragma unroll
        for (int d = 0; d < 8; ++d) {
            qf[d] = softplusf(qf[d]);
            kf[d] = softplusf(kf[d]);
            kls[t * 9 + d] = kf[d];
            vls[t * 9 + d] = vf[d];
        }
    }
    __syncthreads();
    if (t < 64) {
        int e = t >> 3, dd = t & 7;
        float s = 0.f;
        for (int c = 0; c < 192; ++c) s += kls[c * 9 + e] * vls[c * 9 + dd];
        sls[t] = s;
    }
    __syncthreads();
    if (t < 192) {
        float rf[8];
        #pragma unroll
        for (int d = 0; d < 8; ++d) {
            float s = 0.f;
            #pragma unroll
            for (int e = 0; e < 8; ++e) s += qf[e] * sls[e * 8 + d];
            rf[d] = s;
        }
        half_t* xr = &xls[t * 65];
        for (int p = 0; p < 64; ++p) {
            float a = boL[p];
            #pragma unroll
            for (int d = 0; d < 8; ++d) a += rf[d] * woL[d * 64 + p];
            xr[p] = (half_t)((float)xr[p] + a);
        }
    }
    __syncthreads();
    half_t* dst = featN + ((size_t)b * 65536 + (size_t)n * 64) * 192;
    for (int i = 0; i < 48; ++i) {
        int idx = t + i * 256;                 // 0..12287 = p*192 + c
        int p = idx / 192, c = idx - p * 192;
        dst[idx] = xls[c * 65 + p];
    }
}

// ---------------------------------------------------------------------------
// conv1: 1x1 192->768 + leaky. GEMM M=65536 (one batch), N=768, K=192.
// ---------------------------------------------------------------------------
__global__ __launch_bounds__(256, 2)
void conv1_kernel(const half_t* __restrict__ featN, const half_t* __restrict__ B1w,
                  const float* __restrict__ b1, half_t* __restrict__ h1p, int batch)
{
    __shared__ half_t As[128 * 64];
    __shared__ half_t Bs[128 * 64];
    const int t = threadIdx.x;
    const int lane = t & 63;
    const int w = t >> 6;
    const int m0 = blockIdx.x * 128;
    const int n0 = blockIdx.y * 128;
    const int wm = (w >> 1) * 64, wn = (w & 1) * 64;
    const int rbase = t >> 3;
    const int g = (t & 7) ^ (rbase & 7);
    const int ar = lane & 15, kc = lane >> 4;

    f32x4 acc[4][4];
    #pragma unroll
    for (int i = 0; i < 4; ++i)
        #pragma unroll
        for (int j = 0; j < 4; ++j) acc[i][j] = (f32x4){0.f, 0.f, 0.f, 0.f};

    const size_t mb = (size_t)batch * 65536 + m0;

    for (int s = 0; s < 3; ++s) {
        const int k0 = s * 64;
        const half_t* ga = featN + (mb + rbase) * 192 + k0 + g * 8;
        const half_t* gb = B1w + (size_t)(n0 + rbase) * 192 + k0 + g * 8;
        half_t* la = As + t * 8;
        half_t* lb = Bs + t * 8;
        #pragma unroll
        for (int i = 0; i < 4; ++i) {
            stage16(ga + (size_t)32 * i * 192, la + 2048 * i);
            stage16(gb + (size_t)32 * i * 192, lb + 2048 * i);
        }
        __syncthreads();
        #pragma unroll
        for (int kh = 0; kh < 2; ++kh) {
            f16x8 af[4], bfr[4];
            const int c = kh * 4 + kc;
            #pragma unroll
            for (int mf = 0; mf < 4; ++mf) {
                int r = wm + mf * 16 + ar;
                af[mf] = *(const f16x8*)&As[(r * 8 + (c ^ (r & 7))) * 8];
            }
            #pragma unroll
            for (int nf = 0; nf < 4; ++nf) {
                int r = wn + nf * 16 + ar;
                bfr[nf] = *(const f16x8*)&Bs[(r * 8 + (c ^ (r & 7))) * 8];
            }
            #pragma unroll
            for (int mf = 0; mf < 4; ++mf)
                #pragma unroll
                for (int nf = 0; nf < 4; ++nf)
                    acc[mf][nf] = __builtin_amdgcn_mfma_f32_16x16x32_f16(af[mf], bfr[nf], acc[mf][nf], 0, 0, 0);
        }
        __syncthreads();
    }

    const int y = m0 >> 8, x0 = m0 & 255;
    half_t* outrow = h1p + ((size_t)(y + 1) * 258 + (x0 + 1)) * 768;
    #pragma unroll
    for (int nf = 0; nf < 4; ++nf) {
        int n = n0 + wn + nf * 16 + ar;
        float bias = b1[n];
        #pragma unroll
        for (int mf = 0; mf < 4; ++mf) {
            #pragma unroll
            for (int r4 = 0; r4 < 4; ++r4) {
                int local = wm + mf * 16 + kc * 4 + r4;
                outrow[(size_t)local * 768 + n] = (half_t)leaky(acc[mf][nf][r4] + bias);
            }
        }
    }
}

// ---------------------------------------------------------------------------
// conv2: 3x3 SAME 768->768 + leaky, implicit GEMM, 256x256 tile, BK=32,
// 8 waves, 4-slot LDS ring, counted vmcnt(8) (never 0 in steady state),
// one raw s_barrier per K-tile, setprio around MFMA clusters.
// Ring safety: slot (t+3)&3 was last ds_read at K-tile t-1; the t-barrier
// separates those reads from this stage's issue.
// ---------------------------------------------------------------------------
__device__ __forceinline__ void conv2_stage(const half_t* __restrict__ h1p,
    const half_t* __restrict__ B2w, half_t* As, half_t* Bs,
    int sk, int y, int n0, int t, int r0, int cg)
{
    const int buf = sk & 3;
    const int tap = sk / 24;
    const int icc = sk - tap * 24;
    const int ky = tap / 3, kx = tap - ky * 3;
    const int ic0 = icc * 32;
    const half_t* gaB = h1p + ((size_t)(y + ky) * 258 + kx) * 768 + ic0 + cg;
    const half_t* gbB = B2w + (size_t)n0 * 6912 + (size_t)tap * 768 + ic0 + cg;
    half_t* la = As + buf * 8192 + t * 8;
    half_t* lb = Bs + buf * 8192 + t * 8;
    stage16(gaB + (size_t)r0 * 768, la);
    stage16(gaB + (size_t)(r0 + 128) * 768, la + 4096);
    stage16(gbB + (size_t)r0 * 6912, lb);
    stage16(gbB + (size_t)(r0 + 128) * 6912, lb + 4096);
}

__device__ __forceinline__ f16x8 ldsfrag(const half_t* base, int row, int kc) {
    // read swizzle: chunk' = kc ^ ((row>>1)&3); matches the pre-swizzled
    // global source (cg) used at stage time (both-sides-or-neither rule)
    return *(const f16x8*)&base[row * 32 + ((kc ^ ((row >> 1) & 3)) << 3)];
}

#define CONV2_STEP(KT, VMN, DO_STAGE)                                              \
  {                                                                                \
    asm volatile("s_waitcnt vmcnt(" VMN ")" ::: "memory");                         \
    __builtin_amdgcn_s_barrier();                                                  \
    if (DO_STAGE) conv2_stage(h1p, B2w, As, Bs, (KT) + 3, y, n0, t, r0, cg);       \
    {                                                                              \
      const half_t* A_ = As + ((KT) & 3) * 8192;                                   \
      const half_t* B_ = Bs + ((KT) & 3) * 8192;                                   \
      f16x8 af[4], bfv[4];                                                         \
      _Pragma("unroll")                                                            \
      for (int i = 0; i < 4; ++i) af[i] = ldsfrag(A_, arow + i * 16, kc);          \
      _Pragma("unroll")                                                            \
      for (int i = 0; i < 4; ++i) bfv[i] = ldsfrag(B_, bcol + i * 16, kc);         \
      __builtin_amdgcn_s_setprio(1);                                               \
      _Pragma("unroll")                                                            \
      for (int mf = 0; mf < 4; ++mf)                                               \
        _Pragma("unroll")                                                          \
        for (int nf = 0; nf < 4; ++nf)                                             \
          acc[mf][nf] = __builtin_amdgcn_mfma_f32_16x16x32_f16(af[mf], bfv[nf], acc[mf][nf], 0, 0, 0); \
      __builtin_amdgcn_s_setprio(0);                                               \
      _Pragma("unroll")                                                            \
      for (int i = 0; i < 4; ++i) af[i] = ldsfrag(A_, arow + (4 + i) * 16, kc);    \
      __builtin_amdgcn_s_setprio(1);                                               \
      _Pragma("unroll")                                                            \
      for (int mf = 0; mf < 4; ++mf)                                               \
        _Pragma("unroll")                                                          \
        for (int nf = 0; nf < 4; ++nf)                                             \
          acc[4 + mf][nf] = __builtin_amdgcn_mfma_f32_16x16x32_f16(af[mf], bfv[nf], acc[4 + mf][nf], 0, 0, 0); \
      __builtin_amdgcn_s_setprio(0);                                               \
    }                                                                              \
  }

__global__ __launch_bounds__(512, 2)
void conv2_kernel(const half_t* __restrict__ h1p, const half_t* __restrict__ B2w,
                  const float* __restrict__ b2, half_t* __restrict__ h2)
{
    __shared__ half_t As[4 * 8192];    // 4 ring slots x [256 rows][32 k] f16
    __shared__ half_t Bs[4 * 8192];

    const int t = threadIdx.x;
    const int lane = t & 63;
    const int w = t >> 6;
    const int wm2 = w >> 2, wn2 = w & 3;         // 2M x 4N wave grid
    const int ar = lane & 15, kc = lane >> 4;
    const int r0 = t >> 2;                        // staging row (j=0)
    const int cg = ((t & 3) ^ ((t >> 3) & 3)) << 3;  // inverse-swizzled src chunk

    // n-innermost + XCD-chunked m: each XCD gets a contiguous 32-row y-band
    const int bid = blockIdx.x;
    const int xcd = bid & 7, sid = bid >> 3;
    const int wg = xcd * 96 + sid;                // 768 = 8 XCD * 96
    const int mtile = wg / 3;
    const int nt = wg - mtile * 3;
    const int y = mtile;                          // BM=256 = one image row
    const int m0 = mtile * 256;
    const int n0 = nt * 256;
    const int arow = wm2 * 128 + ar;
    const int bcol = wn2 * 64 + ar;

    f32x4 acc[8][4];
    #pragma unroll
    for (int i = 0; i < 8; ++i)
        #pragma unroll
        for (int j = 0; j < 4; ++j) acc[i][j] = (f32x4){0.f, 0.f, 0.f, 0.f};

    // prologue: stage K-tiles 0,1,2 into ring slots 0,1,2
    conv2_stage(h1p, B2w, As, Bs, 0, y, n0, t, r0, cg);
    conv2_stage(h1p, B2w, As, Bs, 1, y, n0, t, r0, cg);
    conv2_stage(h1p, B2w, As, Bs, 2, y, n0, t, r0, cg);

    // steady state: 216 K-tiles total (9 taps x 24 ic-chunks of 32)
    for (int kt = 0; kt < 213; ++kt) CONV2_STEP(kt, "8", true);
    CONV2_STEP(213, "8", false);
    CONV2_STEP(214, "4", false);
    CONV2_STEP(215, "0", false);

    const int mbase = m0 + wm2 * 128 + kc * 4;
    #pragma unroll
    for (int nf = 0; nf < 4; ++nf) {
        int col = n0 + wn2 * 64 + nf * 16 + ar;
        float bias = b2[col];
        half_t* op = h2 + (size_t)mbase * 768 + col;
        #pragma unroll
        for (int mf = 0; mf < 8; ++mf)
            #pragma unroll
            for (int r4 = 0; r4 < 4; ++r4)
                op[((size_t)mf * 16 + r4) * 768] = (half_t)leaky(acc[mf][nf][r4] + bias);
    }
}

// ---------------------------------------------------------------------------
// conv3: 1x1 768->192 + leaky. GEMM M=65536 (one batch), N=192, K=768.
// ---------------------------------------------------------------------------
__global__ __launch_bounds__(256, 2)
void conv3_kernel(const half_t* __restrict__ h2, const half_t* __restrict__ B3w,
                  const float* __restrict__ b3, float* __restrict__ out, int batch)
{
    __shared__ half_t As[128 * 64];
    __shared__ half_t Bs[192 * 64];
    const int t = threadIdx.x;
    const int lane = t & 63;
    const int w = t >> 6;
    const int m0 = blockIdx.x * 128;
    const int wm = (w >> 1) * 64;
    const int wn = (w & 1) * 96;
    const int rbase = t >> 3;
    const int g = (t & 7) ^ (rbase & 7);
    const int ar = lane & 15, kc = lane >> 4;

    f32x4 acc[4][6];
    #pragma unroll
    for (int i = 0; i < 4; ++i)
        #pragma unroll
        for (int j = 0; j < 6; ++j) acc[i][j] = (f32x4){0.f, 0.f, 0.f, 0.f};

    for (int s = 0; s < 12; ++s) {
        const int k0 = s * 64;
        const half_t* ga = h2 + (size_t)(m0 + rbase) * 768 + k0 + g * 8;
        const half_t* gb = B3w + (size_t)rbase * 768 + k0 + g * 8;
        half_t* la = As + t * 8;
        half_t* lb = Bs + t * 8;
        #pragma unroll
        for (int i = 0; i < 4; ++i) stage16(ga + (size_t)32 * i * 768, la + 2048 * i);
        #pragma unroll
        for (int i = 0; i < 6; ++i) stage16(gb + (size_t)32 * i * 768, lb + 2048 * i);
        __syncthreads();
        #pragma unroll
        for (int kh = 0; kh < 2; ++kh) {
            f16x8 af[4], bfr[6];
            const int c = kh * 4 + kc;
            #pragma unroll
            for (int mf = 0; mf < 4; ++mf) {
                int r = wm + mf * 16 + ar;
                af[mf] = *(const f16x8*)&As[(r * 8 + (c ^ (r & 7))) * 8];
            }
            #pragma unroll
            for (int nf = 0; nf < 6; ++nf) {
                int r = wn + nf * 16 + ar;
                bfr[nf] = *(const f16x8*)&Bs[(r * 8 + (c ^ (r & 7))) * 8];
            }
            #pragma unroll
            for (int mf = 0; mf < 4; ++mf)
                #pragma unroll
                for (int nf = 0; nf < 6; ++nf)
                    acc[mf][nf] = __builtin_amdgcn_mfma_f32_16x16x32_f16(af[mf], bfr[nf], acc[mf][nf], 0, 0, 0);
        }
        __syncthreads();
    }

    #pragma unroll
    for (int nf = 0; nf < 6; ++nf) {
        int n = wn + nf * 16 + ar;
        float bias = b3[n];
        float* op = out + ((size_t)batch * 192 + n) * 65536 + m0;
        #pragma unroll
        for (int mf = 0; mf < 4; ++mf) {
            int local = wm + mf * 16 + kc * 4;
            f32x4 v;
            #pragma unroll
            for (int r4 = 0; r4 < 4; ++r4) v[r4] = leaky(acc[mf][nf][r4] + bias);
            *(f32x4*)(op + local) = v;
        }
    }
}

// ---------------------------------------------------------------------------
extern "C" void kernel_launch(void* const* d_in, const int* in_sizes, int n_in,
                              void* d_out, int out_size, void* d_ws, size_t ws_size,
                              hipStream_t stream)
{
    const float* x  = (const float*)d_in[0];
    const float* Wq = (const float*)d_in[1];
    const float* bq = (const float*)d_in[2];
    const float* Wk = (const float*)d_in[3];
    const float* bk = (const float*)d_in[4];
    const float* Wv = (const float*)d_in[5];
    const float* bv = (const float*)d_in[6];
    const float* Wo = (const float*)d_in[7];
    const float* bo = (const float*)d_in[8];
    const float* W1 = (const float*)d_in[9];
    const float* b1 = (const float*)d_in[10];
    const float* W2 = (const float*)d_in[11];
    const float* b2 = (const float*)d_in[12];
    const float* W3 = (const float*)d_in[13];
    const float* b3 = (const float*)d_in[14];

    char* ws = (char*)d_ws;
    const size_t OFF_B1   = 0;
    const size_t OFF_B3   = 294912;
    const size_t OFF_B2   = 589824;
    const size_t OFF_FEAT = 11206656;
    const size_t OFF_H1P  = 111869952;
    const size_t OFF_H2   = 214124544;
    const size_t WS_NEED  = 314787840;
    if (ws_size < WS_NEED) return;

    half_t* B1w   = (half_t*)(ws + OFF_B1);
    half_t* B3w   = (half_t*)(ws + OFF_B3);
    half_t* B2w   = (half_t*)(ws + OFF_B2);
    half_t* featN = (half_t*)(ws + OFF_FEAT);
    half_t* h1p   = (half_t*)(ws + OFF_H1P);
    half_t* h2    = (half_t*)(ws + OFF_H2);

    hipMemsetAsync(h1p, 0, 102254592, stream);
    prep_kernel<<<21888, 256, 0, stream>>>(W1, W2, W3, B1w, B2w, B3w);
    attn_kernel<<<4096, 256, 0, stream>>>(x, Wq, bq, Wk, bk, Wv, bv, Wo, bo, featN);

    for (int b = 0; b < 4; ++b) {
        conv1_kernel<<<dim3(512, 6), 256, 0, stream>>>(featN, B1w, b1, h1p, b);
        conv2_kernel<<<768, 512, 0, stream>>>(h1p, B2w, b2, h2);
        conv3_kernel<<<dim3(512, 1), 256, 0, stream>>>(h2, B3w, b3, (float*)d_out, b);
    }
}

// Round 3
// 3150.742 us; speedup vs baseline: 1.1564x; 1.1564x over previous
//
#include <hip/hip_runtime.h>
#include <stdint.h>
#include <math.h>

typedef _Float16 half_t;
typedef _Float16 f16x8 __attribute__((ext_vector_type(8)));
typedef float f32x4 __attribute__((ext_vector_type(4)));

#define SLOPE 0.01f

__device__ inline float leaky(float v) { return v > 0.f ? v : SLOPE * v; }

__device__ inline void stage16(const half_t* g, half_t* l) {
    __builtin_amdgcn_global_load_lds(
        (const __attribute__((address_space(1))) unsigned int*)g,
        (__attribute__((address_space(3))) unsigned int*)l, 16, 0, 0);
}

__device__ inline float softplusf(float v) {
    return v > 20.f ? v : log1pf(expf(v));
}

// ---------------------------------------------------------------------------
// Weight prep: cast/reorder conv weights to oc-major fp16 ("B^T" GEMM operand)
// ---------------------------------------------------------------------------
__global__ void prep_kernel(const float* __restrict__ W1, const float* __restrict__ W2,
                            const float* __restrict__ W3,
                            half_t* __restrict__ B1w, half_t* __restrict__ B2w,
                            half_t* __restrict__ B3w)
{
    const unsigned idx = blockIdx.x * 256u + threadIdx.x;
    const unsigned n2 = 768u * 6912u;                 // 5,308,416
    if (idx < n2) {
        unsigned oc = idx / 6912u;
        unsigned rem = idx - oc * 6912u;
        unsigned tap = rem / 768u;
        unsigned ic = rem - tap * 768u;
        unsigned ky = tap / 3u, kx = tap - ky * 3u;
        B2w[idx] = (half_t)W2[(((size_t)oc * 768u + ic) * 3u + ky) * 3u + kx];
    } else if (idx < n2 + 147456u) {
        unsigned i = idx - n2;
        B1w[i] = (half_t)W1[i];                       // W1 flat is already (oc,ic)
    } else if (idx < n2 + 294912u) {
        unsigned i = idx - n2 - 147456u;
        B3w[i] = (half_t)W3[i];                       // W3 flat is already (oc,ic)
    }
}

// ---------------------------------------------------------------------------
// Per-window linear attention. One block per window. Writes feat NHWC fp16.
// ---------------------------------------------------------------------------
__global__ __launch_bounds__(256, 2)
void attn_kernel(const float* __restrict__ x,
                 const float* __restrict__ Wq, const float* __restrict__ bq,
                 const float* __restrict__ Wk, const float* __restrict__ bk,
                 const float* __restrict__ Wv, const float* __restrict__ bv,
                 const float* __restrict__ Wo, const float* __restrict__ bo,
                 half_t* __restrict__ featN)
{
    __shared__ half_t xls[192 * 65];
    __shared__ float wqL[512], wkL[512], wvL[512], woL[512];
    __shared__ float bqL[8], bkL[8], bvL[8], boL[64];
    __shared__ float kls[192 * 9], vls[192 * 9];
    __shared__ float sls[64];

    const int t = threadIdx.x;
    const int blk = blockIdx.x;
    const int b = blk >> 10;
    const int n = blk & 1023;
    const int wi = n >> 5, wj = n & 31;

    for (int i = t; i < 512; i += 256) {
        wqL[i] = Wq[i]; wkL[i] = Wk[i]; wvL[i] = Wv[i]; woL[i] = Wo[i];
    }
    if (t < 8)  { bqL[t] = bq[t]; bkL[t] = bk[t]; bvL[t] = bv[t]; }
    if (t < 64) boL[t] = bo[t];

    #pragma unroll
    for (int i = 0; i < 6; ++i) {
        int idx = t + i * 256;                 // 0..1535 = (c,py)
        int c = idx >> 3, py = idx & 7;
        const float* src = x + (((size_t)b * 192 + c) * 256 + (wi * 8 + py)) * 256 + wj * 8;
        float4 v0 = *(const float4*)src;
        float4 v1 = *(const float4*)(src + 4);
        half_t* dst = &xls[c * 65 + py * 8];
        dst[0] = (half_t)v0.x; dst[1] = (half_t)v0.y; dst[2] = (half_t)v0.z; dst[3] = (half_t)v0.w;
        dst[4] = (half_t)v1.x; dst[5] = (half_t)v1.y; dst[6] = (half_t)v1.z; dst[7] = (half_t)v1.w;
    }
    __syncthreads();

    float qf[8], kf[8], vf[8];
    if (t < 192) {
        #pragma unroll
        for (int d = 0; d < 8; ++d) { qf[d] = bqL[d]; kf[d] = bkL[d]; vf[d] = bvL[d]; }
        const half_t* xr = &xls[t * 65];
        for (int p = 0; p < 64; ++p) {
            float xv = (float)xr[p];
            const float* wqp = &wqL[p * 8];
            const float* wkp = &wkL[p * 8];
            const float* wvp = &wvL[p * 8];
            #pragma unroll
            for (int d = 0; d < 8; ++d) {
                qf[d] += xv * wqp[d];
                kf[d] += xv * wkp[d];
                vf[d] += xv * wvp[d];
            }
        }
        #pragma unroll
        for (int d = 0; d < 8; ++d) {
            qf[d] = softplusf(qf[d]);
            kf[d] = softplusf(kf[d]);
            kls[t * 9 + d] = kf[d];
            vls[t * 9 + d] = vf[d];
        }
    }
    __syncthreads();
    if (t < 64) {
        int e = t >> 3, dd = t & 7;
        float s = 0.f;
        for (int c = 0; c < 192; ++c) s += kls[c * 9 + e] * vls[c * 9 + dd];
        sls[t] = s;
    }
    __syncthreads();
    if (t < 192) {
        float rf[8];
        #pragma unroll
        for (int d = 0; d < 8; ++d) {
            float s = 0.f;
            #pragma unroll
            for (int e = 0; e < 8; ++e) s += qf[e] * sls[e * 8 + d];
            rf[d] = s;
        }
        half_t* xr = &xls[t * 65];
        for (int p = 0; p < 64; ++p) {
            float a = boL[p];
            #pragma unroll
            for (int d = 0; d < 8; ++d) a += rf[d] * woL[d * 64 + p];
            xr[p] = (half_t)((float)xr[p] + a);
        }
    }
    __syncthreads();
    half_t* dst = featN + ((size_t)b * 65536 + (size_t)n * 64) * 192;
    for (int i = 0; i < 48; ++i) {
        int idx = t + i * 256;                 // 0..12287 = p*192 + c
        int p = idx / 192, c = idx - p * 192;
        dst[idx] = xls[c * 65 + p];
    }
}

// ---------------------------------------------------------------------------
// conv1: 1x1 192->768 + leaky. GEMM M=65536 (one batch), N=768, K=192.
// ---------------------------------------------------------------------------
__global__ __launch_bounds__(256, 2)
void conv1_kernel(const half_t* __restrict__ featN, const half_t* __restrict__ B1w,
                  const float* __restrict__ b1, half_t* __restrict__ h1p, int batch)
{
    __shared__ half_t As[128 * 64];
    __shared__ half_t Bs[128 * 64];
    const int t = threadIdx.x;
    const int lane = t & 63;
    const int w = t >> 6;
    const int m0 = blockIdx.x * 128;
    const int n0 = blockIdx.y * 128;
    const int wm = (w >> 1) * 64, wn = (w & 1) * 64;
    const int rbase = t >> 3;
    const int g = (t & 7) ^ (rbase & 7);
    const int ar = lane & 15, kc = lane >> 4;

    f32x4 acc[4][4];
    #pragma unroll
    for (int i = 0; i < 4; ++i)
        #pragma unroll
        for (int j = 0; j < 4; ++j) acc[i][j] = (f32x4){0.f, 0.f, 0.f, 0.f};

    const size_t mb = (size_t)batch * 65536 + m0;

    for (int s = 0; s < 3; ++s) {
        const int k0 = s * 64;
        const half_t* ga = featN + (mb + rbase) * 192 + k0 + g * 8;
        const half_t* gb = B1w + (size_t)(n0 + rbase) * 192 + k0 + g * 8;
        half_t* la = As + t * 8;
        half_t* lb = Bs + t * 8;
        #pragma unroll
        for (int i = 0; i < 4; ++i) {
            stage16(ga + (size_t)32 * i * 192, la + 2048 * i);
            stage16(gb + (size_t)32 * i * 192, lb + 2048 * i);
        }
        __syncthreads();
        #pragma unroll
        for (int kh = 0; kh < 2; ++kh) {
            f16x8 af[4], bfr[4];
            const int c = kh * 4 + kc;
            #pragma unroll
            for (int mf = 0; mf < 4; ++mf) {
                int r = wm + mf * 16 + ar;
                af[mf] = *(const f16x8*)&As[(r * 8 + (c ^ (r & 7))) * 8];
            }
            #pragma unroll
            for (int nf = 0; nf < 4; ++nf) {
                int r = wn + nf * 16 + ar;
                bfr[nf] = *(const f16x8*)&Bs[(r * 8 + (c ^ (r & 7))) * 8];
            }
            #pragma unroll
            for (int mf = 0; mf < 4; ++mf)
                #pragma unroll
                for (int nf = 0; nf < 4; ++nf)
                    acc[mf][nf] = __builtin_amdgcn_mfma_f32_16x16x32_f16(af[mf], bfr[nf], acc[mf][nf], 0, 0, 0);
        }
        __syncthreads();
    }

    const int y = m0 >> 8, x0 = m0 & 255;
    half_t* outrow = h1p + ((size_t)(y + 1) * 258 + (x0 + 1)) * 768;
    #pragma unroll
    for (int nf = 0; nf < 4; ++nf) {
        int n = n0 + wn + nf * 16 + ar;
        float bias = b1[n];
        #pragma unroll
        for (int mf = 0; mf < 4; ++mf) {
            #pragma unroll
            for (int r4 = 0; r4 < 4; ++r4) {
                int local = wm + mf * 16 + kc * 4 + r4;
                outrow[(size_t)local * 768 + n] = (half_t)leaky(acc[mf][nf][r4] + bias);
            }
        }
    }
}

// ---------------------------------------------------------------------------
// conv2 v3: 3x3 SAME 768->768 + leaky, implicit GEMM.
// 256x256 tile, BK=64, 2 K-steps/iteration, 8-phase schedule (m201 port):
// per phase all 8 waves compute one 128x128 C-quadrant (16 MFMA/wave),
// ds_reads interleaved per phase (12/4/8/4), half-tile staging on the
// free/ready-verified schedule, counted vmcnt(4) at phases 4&8 only.
// LDS: A,B each 2 buf x 2 half x [128][64] f16 = 128 KiB total.
// Swizzle: chunk' = chunk ^ (row&7), linear DMA dest + pre-swizzled source.
// ---------------------------------------------------------------------------
__device__ __forceinline__ void c2_stage_A(half_t* As, int buf, int h,
    const half_t* __restrict__ h1p, int y, int kstep, int t, int cg)
{
    const int tap = kstep / 12, icc = kstep - tap * 12;
    const int ky = tap / 3, kx = tap - ky * 3;
    const int row0 = t >> 3;
    const half_t* g = h1p + ((size_t)(y + ky) * 258 + (kx + h * 128 + row0)) * 768
                      + icc * 64 + cg;
    half_t* l = As + (buf * 2 + h) * 8192 + t * 8;
    stage16(g, l);
    stage16(g + (size_t)64 * 768, l + 4096);
}

__device__ __forceinline__ void c2_stage_B(half_t* Bs, int buf, int h,
    const half_t* __restrict__ B2w, int n0, int kstep, int t, int cg)
{
    const int tap = kstep / 12, icc = kstep - tap * 12;
    const int row0 = t >> 3;
    const half_t* g = B2w + (size_t)(n0 + h * 128 + row0) * 6912
                      + tap * 768 + icc * 64 + cg;
    half_t* l = Bs + (buf * 2 + h) * 8192 + t * 8;
    stage16(g, l);
    stage16(g + (size_t)64 * 6912, l + 4096);
}

// One phase: optional A/B fragment reads, stage code, optional vmcnt,
// barrier, lgkmcnt(0)+sched_barrier (rule #18), setprio'd 16-MFMA, barrier.
#define C2_PHASE(MQ, NQ, BUF, RD_A, RD_B, STAGE_CODE, VMCNT_CODE)                   \
  {                                                                                  \
    if (RD_A) {                                                                      \
      _Pragma("unroll")                                                              \
      for (int mf = 0; mf < 4; ++mf) {                                               \
        _Pragma("unroll")                                                            \
        for (int kh = 0; kh < 2; ++kh) {                                             \
          int lr = wm * 64 + mf * 16 + ar;                                           \
          int ch = (kh * 4 + kc) ^ (lr & 7);                                         \
          af[mf][kh] = *(const f16x8*)&As[((BUF) * 2 + (MQ)) * 8192 + lr * 64 + ch * 8]; \
        }                                                                            \
      }                                                                              \
    }                                                                                \
    if (RD_B) {                                                                      \
      _Pragma("unroll")                                                              \
      for (int nf = 0; nf < 2; ++nf) {                                               \
        _Pragma("unroll")                                                            \
        for (int kh = 0; kh < 2; ++kh) {                                             \
          int lc = wn * 32 + nf * 16 + ar;                                           \
          int ch = (kh * 4 + kc) ^ (lc & 7);                                         \
          bf[nf][kh] = *(const f16x8*)&Bs[((BUF) * 2 + (NQ)) * 8192 + lc * 64 + ch * 8]; \
        }                                                                            \
      }                                                                              \
    }                                                                                \
    STAGE_CODE                                                                       \
    VMCNT_CODE                                                                       \
    __builtin_amdgcn_s_barrier();                                                    \
    asm volatile("s_waitcnt lgkmcnt(0)" ::: "memory");                               \
    __builtin_amdgcn_sched_barrier(0);                                               \
    __builtin_amdgcn_s_setprio(1);                                                   \
    _Pragma("unroll")                                                                \
    for (int kh = 0; kh < 2; ++kh)                                                   \
      _Pragma("unroll")                                                              \
      for (int mf = 0; mf < 4; ++mf)                                                 \
        _Pragma("unroll")                                                            \
        for (int nf = 0; nf < 2; ++nf)                                               \
          acc[(MQ) * 2 + (NQ)][mf][nf] = __builtin_amdgcn_mfma_f32_16x16x32_f16(     \
              af[mf][kh], bf[nf][kh], acc[(MQ) * 2 + (NQ)][mf][nf], 0, 0, 0);        \
    __builtin_amdgcn_s_setprio(0);                                                   \
    __builtin_amdgcn_s_barrier();                                                    \
  }

#define C2_VM4 { asm volatile("s_waitcnt vmcnt(4)" ::: "memory"); }
#define C2_VM0 { asm volatile("s_waitcnt vmcnt(0)" ::: "memory"); }
#define C2_NOP { }

__global__ __launch_bounds__(512, 2)
void conv2_kernel(const half_t* __restrict__ h1p, const half_t* __restrict__ B2w,
                  const float* __restrict__ b2, half_t* __restrict__ h2)
{
    __shared__ half_t As[4 * 8192];    // [buf][half][128][64] f16 = 64 KiB
    __shared__ half_t Bs[4 * 8192];

    const int t = threadIdx.x;
    const int lane = t & 63;
    const int w = t >> 6;
    const int wm = w >> 2, wn = w & 3;            // 2x4 wave grid inside a quadrant
    const int ar = lane & 15, kc = lane >> 4;
    const int cg = (((t & 7) ^ ((t >> 3) & 7)) << 3);  // pre-swizzled source chunk

    // n-innermost + XCD-chunked m: each XCD gets a contiguous 32-row y-band
    const int bid = blockIdx.x;
    const int xcd = bid & 7, sid = bid >> 3;
    const int wg = xcd * 96 + sid;                // 768 = 8 XCD * 96
    const int mtile = wg / 3;
    const int nt = wg - mtile * 3;
    const int y = mtile;                          // BM=256 = one image row
    const int m0 = mtile * 256;
    const int n0 = nt * 256;

    f32x4 acc[4][4][2];                           // [quadrant][mf][nf]
    #pragma unroll
    for (int q = 0; q < 4; ++q)
        #pragma unroll
        for (int i = 0; i < 4; ++i)
            #pragma unroll
            for (int j = 0; j < 2; ++j) acc[q][i][j] = (f32x4){0.f, 0.f, 0.f, 0.f};

    f16x8 af[4][2], bf[2][2];

    // Prologue: kt0(=0) all 4 halves + A1h0,B1h1 of kt1(=1); drain once.
    c2_stage_A(As, 0, 0, h1p, y, 0, t, cg);
    c2_stage_A(As, 0, 1, h1p, y, 0, t, cg);
    c2_stage_B(Bs, 0, 0, B2w, n0, 0, t, cg);
    c2_stage_B(Bs, 0, 1, B2w, n0, 0, t, cg);
    c2_stage_A(As, 1, 0, h1p, y, 1, t, cg);
    c2_stage_B(Bs, 1, 1, B2w, n0, 1, t, cg);
    asm volatile("s_waitcnt vmcnt(0)" ::: "memory");
    __builtin_amdgcn_s_barrier();

    // Steady state: 54 iterations x 2 K-steps; last iteration peeled.
    for (int i = 0; i < 53; ++i) {
        const int k1 = 2 * i + 1;
        const int k2 = 2 * i + 2;
        // ph1 (q00,kt0): stage A1h1,B1h0 <- k1 (read ph7/ph5 this iter)
        C2_PHASE(0, 0, 0, 1, 1,
                 { c2_stage_A(As, 1, 1, h1p, y, k1, t, cg);
                   c2_stage_B(Bs, 1, 0, B2w, n0, k1, t, cg); }, C2_NOP)
        // ph2 (q01,kt0): A kept
        C2_PHASE(0, 1, 0, 0, 1, C2_NOP, C2_NOP)
        // ph3 (q11,kt0): stage A0h0 <- k2 (A0h0 last read ph1)
        C2_PHASE(1, 1, 0, 1, 0,
                 { c2_stage_A(As, 0, 0, h1p, y, k2, t, cg); }, C2_NOP)
        // ph4 (q10,kt0): stage B0h1 <- k2; counted wait
        C2_PHASE(1, 0, 0, 0, 1,
                 { c2_stage_B(Bs, 0, 1, B2w, n0, k2, t, cg); }, C2_VM4)
        // ph5 (q00,kt1): stage A0h1,B0h0 <- k2
        C2_PHASE(0, 0, 1, 1, 1,
                 { c2_stage_A(As, 0, 1, h1p, y, k2, t, cg);
                   c2_stage_B(Bs, 0, 0, B2w, n0, k2, t, cg); }, C2_NOP)
        // ph6 (q01,kt1)
        C2_PHASE(0, 1, 1, 0, 1, C2_NOP, C2_NOP)
        // ph7 (q11,kt1): stage A1h0 <- k1+2
        C2_PHASE(1, 1, 1, 1, 0,
                 { c2_stage_A(As, 1, 0, h1p, y, k1 + 2, t, cg); }, C2_NOP)
        // ph8 (q10,kt1): stage B1h1 <- k1+2; counted wait
        C2_PHASE(1, 0, 1, 0, 1,
                 { c2_stage_B(Bs, 1, 1, B2w, n0, k1 + 2, t, cg); }, C2_VM4)
    }
    // i = 53 (k0=106, k1=107): only ph1's stages are in-range (gen 107).
    C2_PHASE(0, 0, 0, 1, 1,
             { c2_stage_A(As, 1, 1, h1p, y, 107, t, cg);
               c2_stage_B(Bs, 1, 0, B2w, n0, 107, t, cg); }, C2_NOP)
    C2_PHASE(0, 1, 0, 0, 1, C2_NOP, C2_NOP)
    C2_PHASE(1, 1, 0, 1, 0, C2_NOP, C2_NOP)
    C2_PHASE(1, 0, 0, 0, 1, C2_NOP, C2_VM0)
    C2_PHASE(0, 0, 1, 1, 1, C2_NOP, C2_NOP)
    C2_PHASE(0, 1, 1, 0, 1, C2_NOP, C2_NOP)
    C2_PHASE(1, 1, 1, 1, 0, C2_NOP, C2_NOP)
    C2_PHASE(1, 0, 1, 0, 1, C2_NOP, C2_NOP)

    // Epilogue: bias + leaky, write NHWC fp16.
    #pragma unroll
    for (int q = 0; q < 4; ++q) {
        const int mq = q >> 1, nq = q & 1;
        #pragma unroll
        for (int nf = 0; nf < 2; ++nf) {
            const int col = n0 + nq * 128 + wn * 32 + nf * 16 + ar;
            const float bias = b2[col];
            #pragma unroll
            for (int mf = 0; mf < 4; ++mf) {
                const int row = m0 + mq * 128 + wm * 64 + mf * 16 + kc * 4;
                half_t* op = h2 + (size_t)row * 768 + col;
                #pragma unroll
                for (int r4 = 0; r4 < 4; ++r4)
                    op[(size_t)r4 * 768] = (half_t)leaky(acc[q][mf][nf][r4] + bias);
            }
        }
    }
}

// ---------------------------------------------------------------------------
// conv3: 1x1 768->192 + leaky. GEMM M=65536 (one batch), N=192, K=768.
// ---------------------------------------------------------------------------
__global__ __launch_bounds__(256, 2)
void conv3_kernel(const half_t* __restrict__ h2, const half_t* __restrict__ B3w,
                  const float* __restrict__ b3, float* __restrict__ out, int batch)
{
    __shared__ half_t As[128 * 64];
    __shared__ half_t Bs[192 * 64];
    const int t = threadIdx.x;
    const int lane = t & 63;
    const int w = t >> 6;
    const int m0 = blockIdx.x * 128;
    const int wm = (w >> 1) * 64;
    const int wn = (w & 1) * 96;
    const int rbase = t >> 3;
    const int g = (t & 7) ^ (rbase & 7);
    const int ar = lane & 15, kc = lane >> 4;

    f32x4 acc[4][6];
    #pragma unroll
    for (int i = 0; i < 4; ++i)
        #pragma unroll
        for (int j = 0; j < 6; ++j) acc[i][j] = (f32x4){0.f, 0.f, 0.f, 0.f};

    for (int s = 0; s < 12; ++s) {
        const int k0 = s * 64;
        const half_t* ga = h2 + (size_t)(m0 + rbase) * 768 + k0 + g * 8;
        const half_t* gb = B3w + (size_t)rbase * 768 + k0 + g * 8;
        half_t* la = As + t * 8;
        half_t* lb = Bs + t * 8;
        #pragma unroll
        for (int i = 0; i < 4; ++i) stage16(ga + (size_t)32 * i * 768, la + 2048 * i);
        #pragma unroll
        for (int i = 0; i < 6; ++i) stage16(gb + (size_t)32 * i * 768, lb + 2048 * i);
        __syncthreads();
        #pragma unroll
        for (int kh = 0; kh < 2; ++kh) {
            f16x8 af[4], bfr[6];
            const int c = kh * 4 + kc;
            #pragma unroll
            for (int mf = 0; mf < 4; ++mf) {
                int r = wm + mf * 16 + ar;
                af[mf] = *(const f16x8*)&As[(r * 8 + (c ^ (r & 7))) * 8];
            }
            #pragma unroll
            for (int nf = 0; nf < 6; ++nf) {
                int r = wn + nf * 16 + ar;
                bfr[nf] = *(const f16x8*)&Bs[(r * 8 + (c ^ (r & 7))) * 8];
            }
            #pragma unroll
            for (int mf = 0; mf < 4; ++mf)
                #pragma unroll
                for (int nf = 0; nf < 6; ++nf)
                    acc[mf][nf] = __builtin_amdgcn_mfma_f32_16x16x32_f16(af[mf], bfr[nf], acc[mf][nf], 0, 0, 0);
        }
        __syncthreads();
    }

    #pragma unroll
    for (int nf = 0; nf < 6; ++nf) {
        int n = wn + nf * 16 + ar;
        float bias = b3[n];
        float* op = out + ((size_t)batch * 192 + n) * 65536 + m0;
        #pragma unroll
        for (int mf = 0; mf < 4; ++mf) {
            int local = wm + mf * 16 + kc * 4;
            f32x4 v;
            #pragma unroll
            for (int r4 = 0; r4 < 4; ++r4) v[r4] = leaky(acc[mf][nf][r4] + bias);
            *(f32x4*)(op + local) = v;
        }
    }
}

// ---------------------------------------------------------------------------
extern "C" void kernel_launch(void* const* d_in, const int* in_sizes, int n_in,
                              void* d_out, int out_size, void* d_ws, size_t ws_size,
                              hipStream_t stream)
{
    const float* x  = (const float*)d_in[0];
    const float* Wq = (const float*)d_in[1];
    const float* bq = (const float*)d_in[2];
    const float* Wk = (const float*)d_in[3];
    const float* bk = (const float*)d_in[4];
    const float* Wv = (const float*)d_in[5];
    const float* bv = (const float*)d_in[6];
    const float* Wo = (const float*)d_in[7];
    const float* bo = (const float*)d_in[8];
    const float* W1 = (const float*)d_in[9];
    const float* b1 = (const float*)d_in[10];
    const float* W2 = (const float*)d_in[11];
    const float* b2 = (const float*)d_in[12];
    const float* W3 = (const float*)d_in[13];
    const float* b3 = (const float*)d_in[14];

    char* ws = (char*)d_ws;
    const size_t OFF_B1   = 0;
    const size_t OFF_B3   = 294912;
    const size_t OFF_B2   = 589824;
    const size_t OFF_FEAT = 11206656;
    const size_t OFF_H1P  = 111869952;
    const size_t OFF_H2   = 214124544;
    const size_t WS_NEED  = 314787840;
    if (ws_size < WS_NEED) return;

    half_t* B1w   = (half_t*)(ws + OFF_B1);
    half_t* B3w   = (half_t*)(ws + OFF_B3);
    half_t* B2w   = (half_t*)(ws + OFF_B2);
    half_t* featN = (half_t*)(ws + OFF_FEAT);
    half_t* h1p   = (half_t*)(ws + OFF_H1P);
    half_t* h2    = (half_t*)(ws + OFF_H2);

    hipMemsetAsync(h1p, 0, 102254592, stream);
    prep_kernel<<<21888, 256, 0, stream>>>(W1, W2, W3, B1w, B2w, B3w);
    attn_kernel<<<4096, 256, 0, stream>>>(x, Wq, bq, Wk, bk, Wv, bv, Wo, bo, featN);

    for (int b = 0; b < 4; ++b) {
        conv1_kernel<<<dim3(512, 6), 256, 0, stream>>>(featN, B1w, b1, h1p, b);
        conv2_kernel<<<768, 512, 0, stream>>>(h1p, B2w, b2, h2);
        conv3_kernel<<<dim3(512, 1), 256, 0, stream>>>(h2, B3w, b3, (float*)d_out, b);
    }
}

// Round 4
// 2906.791 us; speedup vs baseline: 1.2535x; 1.0839x over previous
//
#include <hip/hip_runtime.h>
#include <stdint.h>
#include <math.h>

typedef _Float16 half_t;
typedef _Float16 f16x8 __attribute__((ext_vector_type(8)));
typedef float f32x4 __attribute__((ext_vector_type(4)));

#define SLOPE 0.01f

__device__ inline float leaky(float v) { return v > 0.f ? v : SLOPE * v; }

__device__ inline void stage16(const half_t* g, half_t* l) {
    __builtin_amdgcn_global_load_lds(
        (const __attribute__((address_space(1))) unsigned int*)g,
        (__attribute__((address_space(3))) unsigned int*)l, 16, 0, 0);
}

__device__ inline float softplusf(float v) {
    return v > 20.f ? v : log1pf(expf(v));
}

// ---------------------------------------------------------------------------
// Weight prep: cast/reorder conv weights to oc-major fp16 ("B^T" GEMM operand)
// ---------------------------------------------------------------------------
__global__ void prep_kernel(const float* __restrict__ W1, const float* __restrict__ W2,
                            const float* __restrict__ W3,
                            half_t* __restrict__ B1w, half_t* __restrict__ B2w,
                            half_t* __restrict__ B3w)
{
    const unsigned idx = blockIdx.x * 256u + threadIdx.x;
    const unsigned n2 = 768u * 6912u;                 // 5,308,416
    if (idx < n2) {
        unsigned oc = idx / 6912u;
        unsigned rem = idx - oc * 6912u;
        unsigned tap = rem / 768u;
        unsigned ic = rem - tap * 768u;
        unsigned ky = tap / 3u, kx = tap - ky * 3u;
        B2w[idx] = (half_t)W2[(((size_t)oc * 768u + ic) * 3u + ky) * 3u + kx];
    } else if (idx < n2 + 147456u) {
        unsigned i = idx - n2;
        B1w[i] = (half_t)W1[i];                       // W1 flat is already (oc,ic)
    } else if (idx < n2 + 294912u) {
        unsigned i = idx - n2 - 147456u;
        B3w[i] = (half_t)W3[i];                       // W3 flat is already (oc,ic)
    }
}

// ---------------------------------------------------------------------------
// Per-window linear attention. One block per window. Writes feat NHWC fp16.
// ---------------------------------------------------------------------------
__global__ __launch_bounds__(256, 2)
void attn_kernel(const float* __restrict__ x,
                 const float* __restrict__ Wq, const float* __restrict__ bq,
                 const float* __restrict__ Wk, const float* __restrict__ bk,
                 const float* __restrict__ Wv, const float* __restrict__ bv,
                 const float* __restrict__ Wo, const float* __restrict__ bo,
                 half_t* __restrict__ featN)
{
    __shared__ half_t xls[192 * 65];
    __shared__ float wqL[512], wkL[512], wvL[512], woL[512];
    __shared__ float bqL[8], bkL[8], bvL[8], boL[64];
    __shared__ float kls[192 * 9], vls[192 * 9];
    __shared__ float sls[64];

    const int t = threadIdx.x;
    const int blk = blockIdx.x;
    const int b = blk >> 10;
    const int n = blk & 1023;
    const int wi = n >> 5, wj = n & 31;

    for (int i = t; i < 512; i += 256) {
        wqL[i] = Wq[i]; wkL[i] = Wk[i]; wvL[i] = Wv[i]; woL[i] = Wo[i];
    }
    if (t < 8)  { bqL[t] = bq[t]; bkL[t] = bk[t]; bvL[t] = bv[t]; }
    if (t < 64) boL[t] = bo[t];

    #pragma unroll
    for (int i = 0; i < 6; ++i) {
        int idx = t + i * 256;                 // 0..1535 = (c,py)
        int c = idx >> 3, py = idx & 7;
        const float* src = x + (((size_t)b * 192 + c) * 256 + (wi * 8 + py)) * 256 + wj * 8;
        float4 v0 = *(const float4*)src;
        float4 v1 = *(const float4*)(src + 4);
        half_t* dst = &xls[c * 65 + py * 8];
        dst[0] = (half_t)v0.x; dst[1] = (half_t)v0.y; dst[2] = (half_t)v0.z; dst[3] = (half_t)v0.w;
        dst[4] = (half_t)v1.x; dst[5] = (half_t)v1.y; dst[6] = (half_t)v1.z; dst[7] = (half_t)v1.w;
    }
    __syncthreads();

    float qf[8], kf[8], vf[8];
    if (t < 192) {
        #pragma unroll
        for (int d = 0; d < 8; ++d) { qf[d] = bqL[d]; kf[d] = bkL[d]; vf[d] = bvL[d]; }
        const half_t* xr = &xls[t * 65];
        for (int p = 0; p < 64; ++p) {
            float xv = (float)xr[p];
            const float* wqp = &wqL[p * 8];
            const float* wkp = &wkL[p * 8];
            const float* wvp = &wvL[p * 8];
            #pragma unroll
            for (int d = 0; d < 8; ++d) {
                qf[d] += xv * wqp[d];
                kf[d] += xv * wkp[d];
                vf[d] += xv * wvp[d];
            }
        }
        #pragma unroll
        for (int d = 0; d < 8; ++d) {
            qf[d] = softplusf(qf[d]);
            kf[d] = softplusf(kf[d]);
            kls[t * 9 + d] = kf[d];
            vls[t * 9 + d] = vf[d];
        }
    }
    __syncthreads();
    if (t < 64) {
        int e = t >> 3, dd = t & 7;
        float s = 0.f;
        for (int c = 0; c < 192; ++c) s += kls[c * 9 + e] * vls[c * 9 + dd];
        sls[t] = s;
    }
    __syncthreads();
    if (t < 192) {
        float rf[8];
        #pragma unroll
        for (int d = 0; d < 8; ++d) {
            float s = 0.f;
            #pragma unroll
            for (int e = 0; e < 8; ++e) s += qf[e] * sls[e * 8 + d];
            rf[d] = s;
        }
        half_t* xr = &xls[t * 65];
        for (int p = 0; p < 64; ++p) {
            float a = boL[p];
            #pragma unroll
            for (int d = 0; d < 8; ++d) a += rf[d] * woL[d * 64 + p];
            xr[p] = (half_t)((float)xr[p] + a);
        }
    }
    __syncthreads();
    half_t* dst = featN + ((size_t)b * 65536 + (size_t)n * 64) * 192;
    for (int i = 0; i < 48; ++i) {
        int idx = t + i * 256;                 // 0..12287 = p*192 + c
        int p = idx / 192, c = idx - p * 192;
        dst[idx] = xls[c * 65 + p];
    }
}

// ---------------------------------------------------------------------------
// conv1: 1x1 192->768 + leaky. GEMM M=65536 (one batch), N=768, K=192.
// ---------------------------------------------------------------------------
__global__ __launch_bounds__(256, 2)
void conv1_kernel(const half_t* __restrict__ featN, const half_t* __restrict__ B1w,
                  const float* __restrict__ b1, half_t* __restrict__ h1p, int batch)
{
    __shared__ half_t As[128 * 64];
    __shared__ half_t Bs[128 * 64];
    const int t = threadIdx.x;
    const int lane = t & 63;
    const int w = t >> 6;
    const int m0 = blockIdx.x * 128;
    const int n0 = blockIdx.y * 128;
    const int wm = (w >> 1) * 64, wn = (w & 1) * 64;
    const int rbase = t >> 3;
    const int g = (t & 7) ^ (rbase & 7);
    const int ar = lane & 15, kc = lane >> 4;

    f32x4 acc[4][4];
    #pragma unroll
    for (int i = 0; i < 4; ++i)
        #pragma unroll
        for (int j = 0; j < 4; ++j) acc[i][j] = (f32x4){0.f, 0.f, 0.f, 0.f};

    const size_t mb = (size_t)batch * 65536 + m0;

    for (int s = 0; s < 3; ++s) {
        const int k0 = s * 64;
        const half_t* ga = featN + (mb + rbase) * 192 + k0 + g * 8;
        const half_t* gb = B1w + (size_t)(n0 + rbase) * 192 + k0 + g * 8;
        half_t* la = As + t * 8;
        half_t* lb = Bs + t * 8;
        #pragma unroll
        for (int i = 0; i < 4; ++i) {
            stage16(ga + (size_t)32 * i * 192, la + 2048 * i);
            stage16(gb + (size_t)32 * i * 192, lb + 2048 * i);
        }
        __syncthreads();
        #pragma unroll
        for (int kh = 0; kh < 2; ++kh) {
            f16x8 af[4], bfr[4];
            const int c = kh * 4 + kc;
            #pragma unroll
            for (int mf = 0; mf < 4; ++mf) {
                int r = wm + mf * 16 + ar;
                af[mf] = *(const f16x8*)&As[(r * 8 + (c ^ (r & 7))) * 8];
            }
            #pragma unroll
            for (int nf = 0; nf < 4; ++nf) {
                int r = wn + nf * 16 + ar;
                bfr[nf] = *(const f16x8*)&Bs[(r * 8 + (c ^ (r & 7))) * 8];
            }
            #pragma unroll
            for (int mf = 0; mf < 4; ++mf)
                #pragma unroll
                for (int nf = 0; nf < 4; ++nf)
                    acc[mf][nf] = __builtin_amdgcn_mfma_f32_16x16x32_f16(af[mf], bfr[nf], acc[mf][nf], 0, 0, 0);
        }
        __syncthreads();
    }

    const int y = m0 >> 8, x0 = m0 & 255;
    half_t* outrow = h1p + ((size_t)(y + 1) * 258 + (x0 + 1)) * 768;
    #pragma unroll
    for (int nf = 0; nf < 4; ++nf) {
        int n = n0 + wn + nf * 16 + ar;
        float bias = b1[n];
        #pragma unroll
        for (int mf = 0; mf < 4; ++mf) {
            #pragma unroll
            for (int r4 = 0; r4 < 4; ++r4) {
                int local = wm + mf * 16 + kc * 4 + r4;
                outrow[(size_t)local * 768 + n] = (half_t)leaky(acc[mf][nf][r4] + bias);
            }
        }
    }
}

// ---------------------------------------------------------------------------
// conv2 v4: 3x3 SAME 768->768 + leaky, implicit GEMM, 256x256 tile, BK=64,
// 8-phase schedule WITH fragment read-ahead: every phase's MFMA operands were
// ds_read-issued >=1 phase earlier, so LDS delivery overlaps MFMA.
// Reads = 24/K-step/wave (floor). Stage slots ph2/ph4/ph6/ph8 (4 loads each),
// counted vmcnt(8) at ph4/ph8; next-buffer frag reads post-MFMA at ph4/ph8
// (after the vmcnt+barrier that proves the buffer landed).
// lgkm waits: ph1(12) ph2(8) ph3(0) ph4(-) ph5(12) ph6(8) ph7(0) ph8(-).
// ---------------------------------------------------------------------------
__device__ __forceinline__ void c2_stage_A(half_t* As, int buf, int h,
    const half_t* __restrict__ h1p, int y, int kstep, int t, int cg)
{
    const int tap = kstep / 12, icc = kstep - tap * 12;
    const int ky = tap / 3, kx = tap - ky * 3;
    const int row0 = t >> 3;
    const half_t* g = h1p + ((size_t)(y + ky) * 258 + (kx + h * 128 + row0)) * 768
                      + icc * 64 + cg;
    half_t* l = As + (buf * 2 + h) * 8192 + t * 8;
    stage16(g, l);
    stage16(g + (size_t)64 * 768, l + 4096);
}

__device__ __forceinline__ void c2_stage_B(half_t* Bs, int buf, int h,
    const half_t* __restrict__ B2w, int n0, int kstep, int t, int cg)
{
    const int tap = kstep / 12, icc = kstep - tap * 12;
    const int row0 = t >> 3;
    const half_t* g = B2w + (size_t)(n0 + h * 128 + row0) * 6912
                      + tap * 768 + icc * 64 + cg;
    half_t* l = Bs + (buf * 2 + h) * 8192 + t * 8;
    stage16(g, l);
    stage16(g + (size_t)64 * 6912, l + 4096);
}

#define SBAR __builtin_amdgcn_s_barrier()
#define SB0  __builtin_amdgcn_sched_barrier(0)
#define LGKM(N) asm volatile("s_waitcnt lgkmcnt(" #N ")" ::: "memory")
#define VMC(N)  asm volatile("s_waitcnt vmcnt(" #N ")" ::: "memory")

// 8 ds_read_b128 into af[MQ] (frags for both kh of quadrant row-half MQ)
#define RDA(MQ, BUF)                                                             \
  _Pragma("unroll")                                                              \
  for (int mf = 0; mf < 4; ++mf)                                                 \
    _Pragma("unroll")                                                            \
    for (int kh = 0; kh < 2; ++kh) {                                             \
      const int lr = wm * 64 + mf * 16 + ar;                                     \
      const int ch = (kh * 4 + kc) ^ (lr & 7);                                   \
      af[MQ][mf][kh] = *(const f16x8*)&As[((BUF)*2 + (MQ))*8192 + lr*64 + ch*8]; \
    }

// 4 ds_read_b128 into bf[NQ]
#define RDB(NQ, BUF)                                                             \
  _Pragma("unroll")                                                              \
  for (int nf = 0; nf < 2; ++nf)                                                 \
    _Pragma("unroll")                                                            \
    for (int kh = 0; kh < 2; ++kh) {                                             \
      const int lc = wn * 32 + nf * 16 + ar;                                     \
      const int ch = (kh * 4 + kc) ^ (lc & 7);                                   \
      bf[NQ][nf][kh] = *(const f16x8*)&Bs[((BUF)*2 + (NQ))*8192 + lc*64 + ch*8]; \
    }

#define MMA16(MQ, NQ)                                                            \
  {                                                                              \
    __builtin_amdgcn_s_setprio(1);                                               \
    _Pragma("unroll")                                                            \
    for (int kh = 0; kh < 2; ++kh)                                               \
      _Pragma("unroll")                                                          \
      for (int mf = 0; mf < 4; ++mf)                                             \
        _Pragma("unroll")                                                        \
        for (int nf = 0; nf < 2; ++nf)                                           \
          acc[(MQ)*2+(NQ)][mf][nf] = __builtin_amdgcn_mfma_f32_16x16x32_f16(     \
              af[MQ][mf][kh], bf[NQ][nf][kh], acc[(MQ)*2+(NQ)][mf][nf], 0, 0, 0);\
    __builtin_amdgcn_s_setprio(0);                                               \
  }

__global__ __launch_bounds__(512, 2)
void conv2_kernel(const half_t* __restrict__ h1p, const half_t* __restrict__ B2w,
                  const float* __restrict__ b2, half_t* __restrict__ h2)
{
    __shared__ half_t As[4 * 8192];    // [buf][half][128][64] f16 = 64 KiB
    __shared__ half_t Bs[4 * 8192];

    const int t = threadIdx.x;
    const int lane = t & 63;
    const int w = t >> 6;
    const int wm = w >> 2, wn = w & 3;            // 2x4 wave grid inside a quadrant
    const int ar = lane & 15, kc = lane >> 4;
    const int cg = (((t & 7) ^ ((t >> 3) & 7)) << 3);  // pre-swizzled source chunk

    // n-innermost + XCD-chunked m
    const int bid = blockIdx.x;
    const int xcd = bid & 7, sid = bid >> 3;
    const int wg = xcd * 96 + sid;                // 768 = 8 XCD * 96
    const int mtile = wg / 3;
    const int nt = wg - mtile * 3;
    const int y = mtile;
    const int m0 = mtile * 256;
    const int n0 = nt * 256;

    f32x4 acc[4][4][2];
    #pragma unroll
    for (int q = 0; q < 4; ++q)
        #pragma unroll
        for (int i = 0; i < 4; ++i)
            #pragma unroll
            for (int j = 0; j < 2; ++j) acc[q][i][j] = (f32x4){0.f, 0.f, 0.f, 0.f};

    f16x8 af[2][4][2];   // [MQ][mf][kh]
    f16x8 bf[2][2][2];   // [NQ][nf][kh]

    // Prologue: stage buf0<-k0, buf1<-k1 fully; drain; issue boundary reads.
    c2_stage_A(As, 0, 0, h1p, y, 0, t, cg);
    c2_stage_A(As, 0, 1, h1p, y, 0, t, cg);
    c2_stage_B(Bs, 0, 0, B2w, n0, 0, t, cg);
    c2_stage_B(Bs, 0, 1, B2w, n0, 0, t, cg);
    c2_stage_A(As, 1, 0, h1p, y, 1, t, cg);
    c2_stage_A(As, 1, 1, h1p, y, 1, t, cg);
    c2_stage_B(Bs, 1, 0, B2w, n0, 1, t, cg);
    c2_stage_B(Bs, 1, 1, B2w, n0, 1, t, cg);
    VMC(0);
    SBAR; SB0;
    RDB(0, 0); SB0;
    RDA(0, 0);

    // Steady: 53 iterations (kt 0..105); tail iteration handles kt 106,107.
    for (int i = 0; i < 53; ++i) {
        const int k2 = 2 * i + 2;
        const int k3 = 2 * i + 3;
        // ph1 (q00 buf0): read-ahead bf1,af1 of buf0.
        RDB(1, 0); SB0;
        RDA(1, 0);
        LGKM(12); SB0;
        MMA16(0, 0);
        SBAR;
        // ph2 (q01 buf0): stage A0h0,B0h0 <- k2.
        c2_stage_A(As, 0, 0, h1p, y, k2, t, cg);
        c2_stage_B(Bs, 0, 0, B2w, n0, k2, t, cg);
        LGKM(8); SB0;
        MMA16(0, 1);
        SBAR;
        // ph3 (q11 buf0).
        LGKM(0); SB0;
        MMA16(1, 1);
        SBAR;
        // ph4 (q10 buf0): stage A0h1,B0h1 <- k2; vmcnt(8); post-reads buf1.
        c2_stage_A(As, 0, 1, h1p, y, k2, t, cg);
        c2_stage_B(Bs, 0, 1, B2w, n0, k2, t, cg);
        VMC(8);
        SBAR; SB0;
        MMA16(1, 0);
        SB0;
        RDB(0, 1); SB0;
        RDA(0, 1);
        SBAR;
        // ph5 (q00 buf1): read-ahead bf1,af1 of buf1.
        RDB(1, 1); SB0;
        RDA(1, 1);
        LGKM(12); SB0;
        MMA16(0, 0);
        SBAR;
        // ph6 (q01 buf1): stage A1h0,B1h0 <- k3.
        c2_stage_A(As, 1, 0, h1p, y, k3, t, cg);
        c2_stage_B(Bs, 1, 0, B2w, n0, k3, t, cg);
        LGKM(8); SB0;
        MMA16(0, 1);
        SBAR;
        // ph7 (q11 buf1).
        LGKM(0); SB0;
        MMA16(1, 1);
        SBAR;
        // ph8 (q10 buf1): stage A1h1,B1h1 <- k3; vmcnt(8); post-reads buf0 next.
        c2_stage_A(As, 1, 1, h1p, y, k3, t, cg);
        c2_stage_B(Bs, 1, 1, B2w, n0, k3, t, cg);
        VMC(8);
        SBAR; SB0;
        MMA16(1, 0);
        SB0;
        RDB(0, 0); SB0;
        RDA(0, 0);
        SBAR;
    }
    // Tail (kt 106,107): no stages, no next-buffer reads.
    {
        // ph1
        RDB(1, 0); SB0;
        RDA(1, 0);
        LGKM(12); SB0;
        MMA16(0, 0);
        SBAR;
        // ph2
        LGKM(8); SB0;
        MMA16(0, 1);
        SBAR;
        // ph3
        LGKM(0); SB0;
        MMA16(1, 1);
        SBAR;
        // ph4: drain all remaining stages (prev ph6/ph8), then buf1 reads.
        VMC(0);
        SBAR; SB0;
        MMA16(1, 0);
        SB0;
        RDB(0, 1); SB0;
        RDA(0, 1);
        SBAR;
        // ph5
        RDB(1, 1); SB0;
        RDA(1, 1);
        LGKM(12); SB0;
        MMA16(0, 0);
        SBAR;
        // ph6
        LGKM(8); SB0;
        MMA16(0, 1);
        SBAR;
        // ph7
        LGKM(0); SB0;
        MMA16(1, 1);
        SBAR;
        // ph8
        MMA16(1, 0);
    }

    // Epilogue: bias + leaky, write NHWC fp16.
    #pragma unroll
    for (int q = 0; q < 4; ++q) {
        const int mq = q >> 1, nq = q & 1;
        #pragma unroll
        for (int nf = 0; nf < 2; ++nf) {
            const int col = n0 + nq * 128 + wn * 32 + nf * 16 + ar;
            const float bias = b2[col];
            #pragma unroll
            for (int mf = 0; mf < 4; ++mf) {
                const int row = m0 + mq * 128 + wm * 64 + mf * 16 + kc * 4;
                half_t* op = h2 + (size_t)row * 768 + col;
                #pragma unroll
                for (int r4 = 0; r4 < 4; ++r4)
                    op[(size_t)r4 * 768] = (half_t)leaky(acc[q][mf][nf][r4] + bias);
            }
        }
    }
}

// ---------------------------------------------------------------------------
// conv3: 1x1 768->192 + leaky. GEMM M=65536 (one batch), N=192, K=768.
// ---------------------------------------------------------------------------
__global__ __launch_bounds__(256, 2)
void conv3_kernel(const half_t* __restrict__ h2, const half_t* __restrict__ B3w,
                  const float* __restrict__ b3, float* __restrict__ out, int batch)
{
    __shared__ half_t As[128 * 64];
    __shared__ half_t Bs[192 * 64];
    const int t = threadIdx.x;
    const int lane = t & 63;
    const int w = t >> 6;
    const int m0 = blockIdx.x * 128;
    const int wm = (w >> 1) * 64;
    const int wn = (w & 1) * 96;
    const int rbase = t >> 3;
    const int g = (t & 7) ^ (rbase & 7);
    const int ar = lane & 15, kc = lane >> 4;

    f32x4 acc[4][6];
    #pragma unroll
    for (int i = 0; i < 4; ++i)
        #pragma unroll
        for (int j = 0; j < 6; ++j) acc[i][j] = (f32x4){0.f, 0.f, 0.f, 0.f};

    for (int s = 0; s < 12; ++s) {
        const int k0 = s * 64;
        const half_t* ga = h2 + (size_t)(m0 + rbase) * 768 + k0 + g * 8;
        const half_t* gb = B3w + (size_t)rbase * 768 + k0 + g * 8;
        half_t* la = As + t * 8;
        half_t* lb = Bs + t * 8;
        #pragma unroll
        for (int i = 0; i < 4; ++i) stage16(ga + (size_t)32 * i * 768, la + 2048 * i);
        #pragma unroll
        for (int i = 0; i < 6; ++i) stage16(gb + (size_t)32 * i * 768, lb + 2048 * i);
        __syncthreads();
        #pragma unroll
        for (int kh = 0; kh < 2; ++kh) {
            f16x8 af[4], bfr[6];
            const int c = kh * 4 + kc;
            #pragma unroll
            for (int mf = 0; mf < 4; ++mf) {
                int r = wm + mf * 16 + ar;
                af[mf] = *(const f16x8*)&As[(r * 8 + (c ^ (r & 7))) * 8];
            }
            #pragma unroll
            for (int nf = 0; nf < 6; ++nf) {
                int r = wn + nf * 16 + ar;
                bfr[nf] = *(const f16x8*)&Bs[(r * 8 + (c ^ (r & 7))) * 8];
            }
            #pragma unroll
            for (int mf = 0; mf < 4; ++mf)
                #pragma unroll
                for (int nf = 0; nf < 6; ++nf)
                    acc[mf][nf] = __builtin_amdgcn_mfma_f32_16x16x32_f16(af[mf], bfr[nf], acc[mf][nf], 0, 0, 0);
        }
        __syncthreads();
    }

    #pragma unroll
    for (int nf = 0; nf < 6; ++nf) {
        int n = wn + nf * 16 + ar;
        float bias = b3[n];
        float* op = out + ((size_t)batch * 192 + n) * 65536 + m0;
        #pragma unroll
        for (int mf = 0; mf < 4; ++mf) {
            int local = wm + mf * 16 + kc * 4;
            f32x4 v;
            #pragma unroll
            for (int r4 = 0; r4 < 4; ++r4) v[r4] = leaky(acc[mf][nf][r4] + bias);
            *(f32x4*)(op + local) = v;
        }
    }
}

// ---------------------------------------------------------------------------
extern "C" void kernel_launch(void* const* d_in, const int* in_sizes, int n_in,
                              void* d_out, int out_size, void* d_ws, size_t ws_size,
                              hipStream_t stream)
{
    const float* x  = (const float*)d_in[0];
    const float* Wq = (const float*)d_in[1];
    const float* bq = (const float*)d_in[2];
    const float* Wk = (const float*)d_in[3];
    const float* bk = (const float*)d_in[4];
    const float* Wv = (const float*)d_in[5];
    const float* bv = (const float*)d_in[6];
    const float* Wo = (const float*)d_in[7];
    const float* bo = (const float*)d_in[8];
    const float* W1 = (const float*)d_in[9];
    const float* b1 = (const float*)d_in[10];
    const float* W2 = (const float*)d_in[11];
    const float* b2 = (const float*)d_in[12];
    const float* W3 = (const float*)d_in[13];
    const float* b3 = (const float*)d_in[14];

    char* ws = (char*)d_ws;
    const size_t OFF_B1   = 0;
    const size_t OFF_B3   = 294912;
    const size_t OFF_B2   = 589824;
    const size_t OFF_FEAT = 11206656;
    const size_t OFF_H1P  = 111869952;
    const size_t OFF_H2   = 214124544;
    const size_t WS_NEED  = 314787840;
    if (ws_size < WS_NEED) return;

    half_t* B1w   = (half_t*)(ws + OFF_B1);
    half_t* B3w   = (half_t*)(ws + OFF_B3);
    half_t* B2w   = (half_t*)(ws + OFF_B2);
    half_t* featN = (half_t*)(ws + OFF_FEAT);
    half_t* h1p   = (half_t*)(ws + OFF_H1P);
    half_t* h2    = (half_t*)(ws + OFF_H2);

    hipMemsetAsync(h1p, 0, 102254592, stream);
    prep_kernel<<<21888, 256, 0, stream>>>(W1, W2, W3, B1w, B2w, B3w);
    attn_kernel<<<4096, 256, 0, stream>>>(x, Wq, bq, Wk, bk, Wv, bv, Wo, bo, featN);

    for (int b = 0; b < 4; ++b) {
        conv1_kernel<<<dim3(512, 6), 256, 0, stream>>>(featN, B1w, b1, h1p, b);
        conv2_kernel<<<768, 512, 0, stream>>>(h1p, B2w, b2, h2);
        conv3_kernel<<<dim3(512, 1), 256, 0, stream>>>(h2, B3w, b3, (float*)d_out, b);
    }
}